// Round 2
// baseline (204.377 us; speedup 1.0000x reference)
//
#include <hip/hip_runtime.h>
#include <hip/hip_bf16.h>

constexpr int B = 4, N = 8192, S = 2048;

typedef __attribute__((ext_vector_type(8))) short short8;
typedef __attribute__((ext_vector_type(4))) float v4f;

__device__ inline float u2f(ushort u) {
    union { ushort u; __hip_bfloat16 h; } c; c.u = u; return __bfloat162float(c.h);
}
__device__ inline ushort f2u(float f) {
    union { ushort u; __hip_bfloat16 h; } c; c.h = __float2bfloat16(f); return c.u;
}
__device__ inline void async_lds16(const void* g, void* l) {
    __builtin_amdgcn_global_load_lds(
        (const __attribute__((address_space(1))) unsigned*)g,
        (__attribute__((address_space(3))) unsigned*)l, 16, 0, 0);
}
__device__ inline short8 ld8(const ushort* p) { return *(const short8*)p; }

// ---------------- prep_all: W pack + pos2 pack + zero sums + both transposes
__device__ inline void transpose_tile(
    const float* __restrict__ ip, ushort* __restrict__ op,
    int L, int C, int l0, int c0, int t, ushort (*tl)[66])
{
    const int lr = t & 63, cb = t >> 6;
    #pragma unroll
    for (int i = 0; i < 16; ++i) {
        int c = cb + 4 * i;
        tl[lr][c] = f2u(ip[(size_t)(c0 + c) * L + l0 + lr]);
    }
    __syncthreads();
    const int cp = t & 31, lrow = t >> 5;
    #pragma unroll
    for (int i = 0; i < 8; ++i) {
        int l = lrow + 8 * i;
        ushort2 v;
        v.x = tl[l][2 * cp]; v.y = tl[l][2 * cp + 1];
        *(ushort2*)(op + (size_t)(l0 + l) * C + c0 + 2 * cp) = v;
    }
}

__global__ __launch_bounds__(256) void prep_all(
    const float* __restrict__ W1, const float* __restrict__ W2,
    const float* __restrict__ pos2, const float* __restrict__ f2,
    const float* __restrict__ f1,
    ushort* __restrict__ W1r, ushort* __restrict__ W2r,
    float4* __restrict__ p2pack, float* __restrict__ zero_region,
    ushort* __restrict__ f2T, ushort* __restrict__ f1T)
{
    __shared__ ushort tl[64][66];
    const int bid = blockIdx.x;
    const int t = threadIdx.x;
    if (bid < 512) {                       // f2: [B,256,S] -> [B,S,256] bf16
        int b = bid >> 7, ct = (bid >> 5) & 3, st = bid & 31;
        transpose_tile(f2 + (size_t)b * 256 * S, f2T + (size_t)b * S * 256,
                       S, 256, st * 64, ct * 64, t, tl);
    } else if (bid < 1536) {               // f1: [B,128,N] -> [B,N,128] bf16
        int u = bid - 512;
        int b = u >> 8, ct = (u >> 7) & 1, lt = u & 127;
        transpose_tile(f1 + (size_t)b * 128 * N, f1T + (size_t)b * N * 128,
                       N, 128, lt * 64, ct * 64, t, tl);
    } else {
        int i = (bid - 1536) * 256 + t;
        if (i < 12288) {                   // W1 chunk-major bf16 pack
            int kk = i >> 10, qq = (i >> 8) & 3, o = i & 255;
            const float* src = W1 + o * 384 + kk * 32 + qq * 8;
            float4 a = *(const float4*)src, bb = *(const float4*)(src + 4);
            union { short8 s; ushort u[8]; } pk;
            pk.u[0]=f2u(a.x); pk.u[1]=f2u(a.y); pk.u[2]=f2u(a.z); pk.u[3]=f2u(a.w);
            pk.u[4]=f2u(bb.x); pk.u[5]=f2u(bb.y); pk.u[6]=f2u(bb.z); pk.u[7]=f2u(bb.w);
            *(short8*)(W1r + i * 8) = pk.s;
        } else if (i < 20480) {            // W2 pack
            int u = i - 12288;
            int kk = u >> 10, qq = (u >> 8) & 3, o = u & 255;
            const float* src = W2 + o * 256 + kk * 32 + qq * 8;
            float4 a = *(const float4*)src, bb = *(const float4*)(src + 4);
            union { short8 s; ushort u[8]; } pk;
            pk.u[0]=f2u(a.x); pk.u[1]=f2u(a.y); pk.u[2]=f2u(a.z); pk.u[3]=f2u(a.w);
            pk.u[4]=f2u(bb.x); pk.u[5]=f2u(bb.y); pk.u[6]=f2u(bb.z); pk.u[7]=f2u(bb.w);
            *(short8*)(W2r + u * 8) = pk.s;
        } else if (i < 21504) {            // zero sums1[512]+sums2[512]
            zero_region[i - 20480] = 0.f;
        } else if (i < 21504 + B * S) {    // pos2 pack as (x,y,z,|p|^2)
            int u = i - 21504;
            int b = u >> 11, s = u & (S - 1);
            float x = pos2[(b * 3 + 0) * S + s];
            float y = pos2[(b * 3 + 1) * S + s];
            float z = pos2[(b * 3 + 2) * S + s];
            p2pack[u] = make_float4(x, y, z, x * x + y * y + z * z);
        }
    }
}

// -------- knn_gemm1: fused 3-NN + interp staging + GEMM1 + stats ----------
// 256 thr, grid (N/64, B). smem: Xs [0,48K), Wbuf [48K,80K).
// knn scratch lives at [64K,72.5K) = Wbuf buffer-1, dead before first use
// of buffer 1 (kk=0 prefetch happens after staging consumed idx/wgt).
__global__ __launch_bounds__(256) void knn_gemm1(
    const float* __restrict__ pos1, const float4* __restrict__ p2pack,
    const ushort* __restrict__ W1r, const float* __restrict__ bias1,
    const ushort* __restrict__ f2T, const ushort* __restrict__ f1T,
    ushort* __restrict__ y, float* __restrict__ sums)
{
    __shared__ __align__(16) char smem[81920];
    ushort* Xs   = (ushort*)smem;
    ushort* Wbuf = (ushort*)(smem + 49152);
    float*  dL   = (float*)(smem + 65536);
    int*    iL   = (int*)  (smem + 65536 + 3072);
    float*  wgtL = (float*)(smem + 65536 + 6144);
    int*    idxL = (int*)  (smem + 65536 + 6912);

    const int t = threadIdx.x;
    const int lane = t & 63;
    const int w = __builtin_amdgcn_readfirstlane(t >> 6);
    const int b = blockIdx.y;
    const int n0 = blockIdx.x * 64;
    const int q = lane >> 4, r = lane & 15, r7 = r & 7;

    // W1 chunk0 prefetch overlaps the knn phase (into Wbuf buffer 0)
    #pragma unroll
    for (int jj = 0; jj < 4; ++jj)
        async_lds16((const char*)W1r + jj * 4096 + t * 16,
                    (char*)Wbuf + jj * 4096 + w * 1024);

    // ---- 3-NN: 4 waves x 512 candidates, lanes = queries ----
    {
        const int qi = n0 + lane;
        const float x1 = pos1[(b * 3 + 0) * N + qi];
        const float y1 = pos1[(b * 3 + 1) * N + qi];
        const float z1 = pos1[(b * 3 + 2) * N + qi];
        const float t1 = x1 * x1 + y1 * y1 + z1 * z1;
        const float4* __restrict__ pp = p2pack + b * S + w * 512;
        float d0 = 3.4e38f, d1 = 3.4e38f, d2 = 3.4e38f;
        int i0 = 0x7fffffff, i1 = 0x7fffffff, i2 = 0x7fffffff;
        #pragma unroll 8
        for (int i = 0; i < 512; ++i) {
            float4 p = pp[i];                       // uniform -> s_load
            float dot = fmaf(x1, p.x, fmaf(y1, p.y, z1 * p.z));
            float dd = fmaf(-2.f, dot, t1) + p.w;
            int s = w * 512 + i;
            bool c0 = dd < d0, c1 = dd < d1, c2 = dd < d2;
            i2 = c1 ? i1 : (c2 ? s : i2);
            i1 = c0 ? i0 : (c1 ? s : i1);
            i0 = c0 ? s : i0;
            float nd1 = __builtin_amdgcn_fmed3f(dd, d0, d1);
            float nd2 = __builtin_amdgcn_fmed3f(dd, d1, d2);
            d0 = fminf(d0, dd);
            d1 = nd1; d2 = nd2;
        }
        int base = (w * 64 + lane) * 3;
        dL[base + 0] = d0; dL[base + 1] = d1; dL[base + 2] = d2;
        iL[base + 0] = i0; iL[base + 1] = i1; iL[base + 2] = i2;
    }
    __syncthreads();
    if (t < 64) {
        float f0 = dL[t*3+0], fv1 = dL[t*3+1], fv2 = dL[t*3+2];
        int   j0 = iL[t*3+0], j1 = iL[t*3+1], j2 = iL[t*3+2];
        #pragma unroll
        for (int c = 1; c < 4; ++c) {
            int cb = (c * 64 + t) * 3;
            #pragma unroll
            for (int k = 0; k < 3; ++k) {
                float d = dL[cb + k]; int id = iL[cb + k];
                bool l0 = (d < f0)  || (d == f0  && id < j0);
                bool l1 = (d < fv1) || (d == fv1 && id < j1);
                bool l2 = (d < fv2) || (d == fv2 && id < j2);
                if (l0)      { fv2 = fv1; j2 = j1; fv1 = f0; j1 = j0; f0 = d; j0 = id; }
                else if (l1) { fv2 = fv1; j2 = j1; fv1 = d; j1 = id; }
                else if (l2) { fv2 = d; j2 = id; }
            }
        }
        float w0 = 1.f / fmaxf(f0, 1e-10f);
        float w1 = 1.f / fmaxf(fv1, 1e-10f);
        float w2 = 1.f / fmaxf(fv2, 1e-10f);
        float inv = 1.f / (w0 + w1 + w2);
        j0 = ((unsigned)j0 < S) ? j0 : 0;
        j1 = ((unsigned)j1 < S) ? j1 : 0;
        j2 = ((unsigned)j2 < S) ? j2 : 0;
        wgtL[t*3+0] = w0 * inv; wgtL[t*3+1] = w1 * inv; wgtL[t*3+2] = w2 * inv;
        idxL[t*3+0] = j0; idxL[t*3+1] = j1; idxL[t*3+2] = j2;
    }
    __syncthreads();

    // ---- X staging: fused interp (idx/wgt from LDS) + f1 tile ----
    {
        const int lp = t & 31, ro = t >> 5;
        #pragma unroll
        for (int it = 0; it < 8; ++it) {
            int rr = ro + 8 * it;
            int s0 = idxL[rr*3+0], s1 = idxL[rr*3+1], s2 = idxL[rr*3+2];
            float w0 = wgtL[rr*3+0], w1 = wgtL[rr*3+1], w2 = wgtL[rr*3+2];
            union { short8 s; ushort u[8]; } a, c, d, o;
            a.s = ld8(f2T + ((size_t)b * S + s0) * 256 + 8 * lp);
            c.s = ld8(f2T + ((size_t)b * S + s1) * 256 + 8 * lp);
            d.s = ld8(f2T + ((size_t)b * S + s2) * 256 + 8 * lp);
            #pragma unroll
            for (int j = 0; j < 8; ++j)
                o.u[j] = f2u(w0 * u2f(a.u[j]) + w1 * u2f(c.u[j]) + w2 * u2f(d.u[j]));
            *(short8*)(Xs + rr * 384 + ((lp ^ ro) * 8)) = o.s;
        }
    }
    {
        const int lp = t & 15, ro = t >> 4;
        #pragma unroll
        for (int it = 0; it < 4; ++it) {
            int rr = ro + 16 * it;
            short8 v = ld8(f1T + ((size_t)b * N + n0 + rr) * 128 + 8 * lp);
            int c = 32 + lp;
            *(short8*)(Xs + rr * 384 + ((c ^ (rr & 7)) * 8)) = v;
        }
    }
    __syncthreads();

    // ---- GEMM1 (K=384, 12 chunks) ----
    v4f acc[4][4];
    #pragma unroll
    for (int mt = 0; mt < 4; ++mt)
        #pragma unroll
        for (int nf = 0; nf < 4; ++nf) acc[mt][nf] = (v4f){0.f, 0.f, 0.f, 0.f};

    for (int kk = 0; kk < 12; ++kk) {
        if (kk < 11) {
            const char* g = (const char*)W1r + (kk + 1) * 16384;
            char* l = (char*)Wbuf + ((kk + 1) & 1) * 16384;
            #pragma unroll
            for (int jj = 0; jj < 4; ++jj)
                async_lds16(g + jj * 4096 + t * 16, l + jj * 4096 + w * 1024);
        }
        const ushort* Wb = Wbuf + (kk & 1) * 8192;
        short8 af[4], bf[4];
        #pragma unroll
        for (int mt = 0; mt < 4; ++mt)
            af[mt] = ld8(Wb + q * 2048 + (w * 64 + mt * 16 + r) * 8);
        #pragma unroll
        for (int nf = 0; nf < 4; ++nf)
            bf[nf] = ld8(Xs + (nf * 16 + r) * 384 + (((kk * 4 + q) ^ r7) * 8));
        #pragma unroll
        for (int mt = 0; mt < 4; ++mt)
            #pragma unroll
            for (int nf = 0; nf < 4; ++nf)
                acc[mt][nf] = __builtin_amdgcn_mfma_f32_16x16x32_bf16(
                    af[mt], bf[nf], acc[mt][nf], 0, 0, 0);
        __syncthreads();
    }

    // ---- epilogue: y -> HBM, stats -> atomics ----
    float* statS = (float*)Xs;
    float* statQ = statS + 256;
    #pragma unroll
    for (int mt = 0; mt < 4; ++mt) {
        int ob = w * 64 + mt * 16 + q * 4;
        float4 bi = *(const float4*)(bias1 + ob);
        float sj0 = 0, sj1 = 0, sj2 = 0, sj3 = 0;
        float qj0 = 0, qj1 = 0, qj2 = 0, qj3 = 0;
        #pragma unroll
        for (int nf = 0; nf < 4; ++nf) {
            int n = n0 + nf * 16 + r;
            float v0 = acc[mt][nf][0] + bi.x, v1 = acc[mt][nf][1] + bi.y;
            float v2 = acc[mt][nf][2] + bi.z, v3 = acc[mt][nf][3] + bi.w;
            ushort4 pk; pk.x = f2u(v0); pk.y = f2u(v1); pk.z = f2u(v2); pk.w = f2u(v3);
            *(ushort4*)(y + ((size_t)b * N + n) * 256 + ob) = pk;
            sj0 += v0; sj1 += v1; sj2 += v2; sj3 += v3;
            qj0 += v0 * v0; qj1 += v1 * v1; qj2 += v2 * v2; qj3 += v3 * v3;
        }
        #pragma unroll
        for (int m = 1; m <= 8; m <<= 1) {
            sj0 += __shfl_xor(sj0, m); sj1 += __shfl_xor(sj1, m);
            sj2 += __shfl_xor(sj2, m); sj3 += __shfl_xor(sj3, m);
            qj0 += __shfl_xor(qj0, m); qj1 += __shfl_xor(qj1, m);
            qj2 += __shfl_xor(qj2, m); qj3 += __shfl_xor(qj3, m);
        }
        if (r == 0) {
            statS[ob + 0] = sj0; statS[ob + 1] = sj1;
            statS[ob + 2] = sj2; statS[ob + 3] = sj3;
            statQ[ob + 0] = qj0; statQ[ob + 1] = qj1;
            statQ[ob + 2] = qj2; statQ[ob + 3] = qj3;
        }
    }
    __syncthreads();
    atomicAdd(&sums[t], statS[t]);
    atomicAdd(&sums[256 + t], statQ[t]);
}

// ------------------------ GEMM2 (BN1+ReLU on load, in-place, fused stats) --
__global__ __launch_bounds__(256) void gemm2_kernel(
    const ushort* __restrict__ Wr, const float* __restrict__ bias,
    const float* __restrict__ sums1, const float* __restrict__ g1,
    const float* __restrict__ be1,
    ushort* __restrict__ y, float* __restrict__ sums)
{
    __shared__ __align__(16) ushort Xs[64 * 256];      // 32 KB
    __shared__ __align__(16) ushort Wbuf[2 * 8192];    // 32 KB
    __shared__ float ssA[256], ssB[256];
    const int t = threadIdx.x;
    const int b = blockIdx.y;
    const int n0 = blockIdx.x * 64;
    const int w = t >> 6, lane = t & 63;
    const int q = lane >> 4, r = lane & 15, r7 = r & 7;

    {
        const char* g0 = (const char*)Wr;
        #pragma unroll
        for (int jj = 0; jj < 4; ++jj)
            async_lds16(g0 + jj * 4096 + t * 16,
                        (char*)Wbuf + jj * 4096 + w * 1024);
    }

    {
        float sv = sums1[t], qv = sums1[256 + t];
        float mean = sv * (1.f / 32768.f);
        float var = qv * (1.f / 32768.f) - mean * mean;
        float rstd = rsqrtf(var + 1e-5f);
        float sc = g1[t] * rstd;
        ssA[t] = sc;
        ssB[t] = be1[t] - mean * sc;
    }
    __syncthreads();

    {
        const int lp = t & 31, ro = t >> 5;
        #pragma unroll
        for (int it = 0; it < 8; ++it) {
            int rr = ro + 8 * it;
            union { short8 s; ushort u[8]; } v, o;
            v.s = ld8(y + ((size_t)b * N + n0 + rr) * 256 + 8 * lp);
            #pragma unroll
            for (int j = 0; j < 8; ++j)
                o.u[j] = f2u(fmaxf(u2f(v.u[j]) * ssA[8 * lp + j] + ssB[8 * lp + j], 0.f));
            *(short8*)(Xs + rr * 256 + ((lp ^ ro) * 8)) = o.s;
        }
    }
    __syncthreads();

    v4f acc[4][4];
    #pragma unroll
    for (int mt = 0; mt < 4; ++mt)
        #pragma unroll
        for (int nf = 0; nf < 4; ++nf) acc[mt][nf] = (v4f){0.f, 0.f, 0.f, 0.f};

    for (int kk = 0; kk < 8; ++kk) {
        if (kk < 7) {
            const char* g = (const char*)Wr + (kk + 1) * 16384;
            char* l = (char*)Wbuf + ((kk + 1) & 1) * 16384;
            #pragma unroll
            for (int jj = 0; jj < 4; ++jj)
                async_lds16(g + jj * 4096 + t * 16, l + jj * 4096 + w * 1024);
        }
        const ushort* Wb = Wbuf + (kk & 1) * 8192;
        short8 af[4], bf[4];
        #pragma unroll
        for (int mt = 0; mt < 4; ++mt)
            af[mt] = ld8(Wb + q * 2048 + (w * 64 + mt * 16 + r) * 8);
        #pragma unroll
        for (int nf = 0; nf < 4; ++nf)
            bf[nf] = ld8(Xs + (nf * 16 + r) * 256 + (((kk * 4 + q) ^ r7) * 8));
        #pragma unroll
        for (int mt = 0; mt < 4; ++mt)
            #pragma unroll
            for (int nf = 0; nf < 4; ++nf)
                acc[mt][nf] = __builtin_amdgcn_mfma_f32_16x16x32_bf16(
                    af[mt], bf[nf], acc[mt][nf], 0, 0, 0);
        __syncthreads();
    }

    float* statS = (float*)Xs;
    float* statQ = statS + 256;
    #pragma unroll
    for (int mt = 0; mt < 4; ++mt) {
        int ob = w * 64 + mt * 16 + q * 4;
        float4 bi = *(const float4*)(bias + ob);
        float sj0 = 0, sj1 = 0, sj2 = 0, sj3 = 0;
        float qj0 = 0, qj1 = 0, qj2 = 0, qj3 = 0;
        #pragma unroll
        for (int nf = 0; nf < 4; ++nf) {
            int n = n0 + nf * 16 + r;
            float v0 = acc[mt][nf][0] + bi.x, v1 = acc[mt][nf][1] + bi.y;
            float v2 = acc[mt][nf][2] + bi.z, v3 = acc[mt][nf][3] + bi.w;
            ushort4 pk; pk.x = f2u(v0); pk.y = f2u(v1); pk.z = f2u(v2); pk.w = f2u(v3);
            *(ushort4*)(y + ((size_t)b * N + n) * 256 + ob) = pk;
            sj0 += v0; sj1 += v1; sj2 += v2; sj3 += v3;
            qj0 += v0 * v0; qj1 += v1 * v1; qj2 += v2 * v2; qj3 += v3 * v3;
        }
        #pragma unroll
        for (int m = 1; m <= 8; m <<= 1) {
            sj0 += __shfl_xor(sj0, m); sj1 += __shfl_xor(sj1, m);
            sj2 += __shfl_xor(sj2, m); sj3 += __shfl_xor(sj3, m);
            qj0 += __shfl_xor(qj0, m); qj1 += __shfl_xor(qj1, m);
            qj2 += __shfl_xor(qj2, m); qj3 += __shfl_xor(qj3, m);
        }
        if (r == 0) {
            statS[ob + 0] = sj0; statS[ob + 1] = sj1;
            statS[ob + 2] = sj2; statS[ob + 3] = sj3;
            statQ[ob + 0] = qj0; statQ[ob + 1] = qj1;
            statQ[ob + 2] = qj2; statQ[ob + 3] = qj3;
        }
    }
    __syncthreads();
    atomicAdd(&sums[t], statS[t]);
    atomicAdd(&sums[256 + t], statQ[t]);
}

// ------------- final: BN2+ReLU + transpose to [B,256,N] fp32 (64x64) ------
__global__ __launch_bounds__(256) void final_kernel(
    const ushort* __restrict__ Y, const float* __restrict__ sums2,
    const float* __restrict__ g2, const float* __restrict__ be2,
    float* __restrict__ out)
{
    __shared__ float tl[64][65];
    __shared__ float ssA[64], ssB[64];
    const int t = threadIdx.x;
    const int b = blockIdx.z;
    const int n0 = blockIdx.x * 64, c0 = blockIdx.y * 64;

    if (t < 64) {
        int c = c0 + t;
        float sv = sums2[c], qv = sums2[256 + c];
        float mean = sv * (1.f / 32768.f);
        float var = qv * (1.f / 32768.f) - mean * mean;
        float rstd = rsqrtf(var + 1e-5f);
        float sc = g2[c] * rstd;
        ssA[t] = sc;
        ssB[t] = be2[c] - mean * sc;
    }
    __syncthreads();

    const int nl = t >> 3, cho = 8 * (t & 7);
    #pragma unroll
    for (int it = 0; it < 2; ++it) {
        int n = nl + 32 * it;
        union { short8 s; ushort u[8]; } v;
        v.s = ld8(Y + ((size_t)b * N + n0 + n) * 256 + c0 + cho);
        #pragma unroll
        for (int j = 0; j < 8; ++j)
            tl[n][cho + j] = fmaxf(u2f(v.u[j]) * ssA[cho + j] + ssB[cho + j], 0.f);
    }
    __syncthreads();

    const int cl = t >> 4, n4 = (t & 15) * 4;
    #pragma unroll
    for (int it = 0; it < 4; ++it) {
        int c = cl + 16 * it;
        float4 v;
        v.x = tl[n4 + 0][c]; v.y = tl[n4 + 1][c];
        v.z = tl[n4 + 2][c]; v.w = tl[n4 + 3][c];
        *(float4*)(out + ((size_t)b * 256 + c0 + c) * N + n0 + n4) = v;
    }
}

// ------------------------------------------------------------ launch -----
extern "C" void kernel_launch(void* const* d_in, const int* in_sizes, int n_in,
                              void* d_out, int out_size, void* d_ws, size_t ws_size,
                              hipStream_t stream)
{
    (void)in_sizes; (void)n_in; (void)out_size;
    if (ws_size < (30u << 20)) return;

    const float* pos1 = (const float*)d_in[0];
    const float* pos2 = (const float*)d_in[1];
    const float* f1   = (const float*)d_in[2];
    const float* f2   = (const float*)d_in[3];
    const float* W1   = (const float*)d_in[4];
    const float* b1   = (const float*)d_in[5];
    const float* g1   = (const float*)d_in[6];
    const float* be1  = (const float*)d_in[7];
    const float* W2   = (const float*)d_in[8];
    const float* b2   = (const float*)d_in[9];
    const float* g2   = (const float*)d_in[10];
    const float* be2  = (const float*)d_in[11];

    char* ws = (char*)d_ws;
    float*  sums1  = (float*)ws;                               // 512 f32
    float*  sums2  = sums1 + 512;                              // 512 f32
    ushort* W1r    = (ushort*)(ws + 4096);                     // 192 KB
    ushort* W2r    = (ushort*)(ws + 4096 + 196608);            // 128 KB
    float4* p2pack = (float4*)(ws + 4096 + 196608 + 131072);   // 128 KB
    ushort* f2T    = (ushort*)(ws + (1u << 19));               // 4 MB
    ushort* f1T    = (ushort*)(ws + (1u << 19) + (4u << 20));  // 8 MB
    ushort* y      = (ushort*)(ws + (1u << 19) + (12u << 20)); // 16 MB

    prep_all<<<1652, 256, 0, stream>>>(W1, W2, pos2, f2, f1,
                                       W1r, W2r, p2pack, sums1, f2T, f1T);

    knn_gemm1<<<dim3(N / 64, B), 256, 0, stream>>>(
        pos1, p2pack, W1r, b1, f2T, f1T, y, sums1);

    gemm2_kernel<<<dim3(N / 64, B), 256, 0, stream>>>(
        W2r, b2, sums1, g1, be1, y, sums2);

    final_kernel<<<dim3(N / 64, 256 / 64, B), 256, 0, stream>>>(
        y, sums2, g2, be2, (float*)d_out);
}

// Round 3
// 185.482 us; speedup vs baseline: 1.1019x; 1.1019x over previous
//
#include <hip/hip_runtime.h>
#include <hip/hip_bf16.h>

constexpr int B = 4, N = 8192, S = 2048;

typedef __attribute__((ext_vector_type(8))) short short8;
typedef __attribute__((ext_vector_type(4))) float v4f;

__device__ inline float u2f(ushort u) {
    union { ushort u; __hip_bfloat16 h; } c; c.u = u; return __bfloat162float(c.h);
}
__device__ inline ushort f2u(float f) {
    union { ushort u; __hip_bfloat16 h; } c; c.h = __float2bfloat16(f); return c.u;
}
__device__ inline void async_lds16(const void* g, void* l) {
    __builtin_amdgcn_global_load_lds(
        (const __attribute__((address_space(1))) unsigned*)g,
        (__attribute__((address_space(3))) unsigned*)l, 16, 0, 0);
}
__device__ inline short8 ld8(const ushort* p) { return *(const short8*)p; }

// ---------------- prep_all: W pack + pos2 pack + zero sums + both transposes
__device__ inline void transpose_tile(
    const float* __restrict__ ip, ushort* __restrict__ op,
    int L, int C, int l0, int c0, int t, ushort (*tl)[66])
{
    const int lr = t & 63, cb = t >> 6;
    #pragma unroll
    for (int i = 0; i < 16; ++i) {
        int c = cb + 4 * i;
        tl[lr][c] = f2u(ip[(size_t)(c0 + c) * L + l0 + lr]);
    }
    __syncthreads();
    const int cp = t & 31, lrow = t >> 5;
    #pragma unroll
    for (int i = 0; i < 8; ++i) {
        int l = lrow + 8 * i;
        ushort2 v;
        v.x = tl[l][2 * cp]; v.y = tl[l][2 * cp + 1];
        *(ushort2*)(op + (size_t)(l0 + l) * C + c0 + 2 * cp) = v;
    }
}

__global__ __launch_bounds__(256) void prep_all(
    const float* __restrict__ W1, const float* __restrict__ W2,
    const float* __restrict__ pos2, const float* __restrict__ f2,
    const float* __restrict__ f1,
    ushort* __restrict__ W1r, ushort* __restrict__ W2r,
    float4* __restrict__ p2pack, float* __restrict__ zero_region,
    ushort* __restrict__ f2T, ushort* __restrict__ f1T)
{
    __shared__ ushort tl[64][66];
    const int bid = blockIdx.x;
    const int t = threadIdx.x;
    if (bid < 512) {                       // f2: [B,256,S] -> [B,S,256] bf16
        int b = bid >> 7, ct = (bid >> 5) & 3, st = bid & 31;
        transpose_tile(f2 + (size_t)b * 256 * S, f2T + (size_t)b * S * 256,
                       S, 256, st * 64, ct * 64, t, tl);
    } else if (bid < 1536) {               // f1: [B,128,N] -> [B,N,128] bf16
        int u = bid - 512;
        int b = u >> 8, ct = (u >> 7) & 1, lt = u & 127;
        transpose_tile(f1 + (size_t)b * 128 * N, f1T + (size_t)b * N * 128,
                       N, 128, lt * 64, ct * 64, t, tl);
    } else {
        int i = (bid - 1536) * 256 + t;
        if (i < 12288) {                   // W1 chunk-major bf16 pack
            int kk = i >> 10, qq = (i >> 8) & 3, o = i & 255;
            const float* src = W1 + o * 384 + kk * 32 + qq * 8;
            float4 a = *(const float4*)src, bb = *(const float4*)(src + 4);
            union { short8 s; ushort u[8]; } pk;
            pk.u[0]=f2u(a.x); pk.u[1]=f2u(a.y); pk.u[2]=f2u(a.z); pk.u[3]=f2u(a.w);
            pk.u[4]=f2u(bb.x); pk.u[5]=f2u(bb.y); pk.u[6]=f2u(bb.z); pk.u[7]=f2u(bb.w);
            *(short8*)(W1r + i * 8) = pk.s;
        } else if (i < 20480) {            // W2 pack
            int u = i - 12288;
            int kk = u >> 10, qq = (u >> 8) & 3, o = u & 255;
            const float* src = W2 + o * 256 + kk * 32 + qq * 8;
            float4 a = *(const float4*)src, bb = *(const float4*)(src + 4);
            union { short8 s; ushort u[8]; } pk;
            pk.u[0]=f2u(a.x); pk.u[1]=f2u(a.y); pk.u[2]=f2u(a.z); pk.u[3]=f2u(a.w);
            pk.u[4]=f2u(bb.x); pk.u[5]=f2u(bb.y); pk.u[6]=f2u(bb.z); pk.u[7]=f2u(bb.w);
            *(short8*)(W2r + u * 8) = pk.s;
        } else if (i < 21504) {            // zero sums1[512]+sums2[512]
            zero_region[i - 20480] = 0.f;
        } else if (i < 21504 + B * S) {    // pos2 pack as (x,y,z,|p|^2)
            int u = i - 21504;
            int b = u >> 11, s = u & (S - 1);
            float x = pos2[(b * 3 + 0) * S + s];
            float y = pos2[(b * 3 + 1) * S + s];
            float z = pos2[(b * 3 + 2) * S + s];
            p2pack[u] = make_float4(x, y, z, x * x + y * y + z * z);
        }
    }
}

// -------- knn_gemm1: fused 3-NN + interp staging + GEMM1 + stats ----------
// 512 thr (8 waves). knn: 8 waves x 256 candidates == baseline arithmetic.
// GEMM1: 8 waves x 32 output channels (mt<2). smem: Xs [0,48K), Wbuf
// [48K,80K). knn scratch at [64K,77.6K) = Wbuf buffer-1, dead before its
// first prefetch (kk=0, after staging consumed idx/wgt).
__global__ __launch_bounds__(512) void knn_gemm1(
    const float* __restrict__ pos1, const float4* __restrict__ p2pack,
    const ushort* __restrict__ W1r, const float* __restrict__ bias1,
    const ushort* __restrict__ f2T, const ushort* __restrict__ f1T,
    ushort* __restrict__ y, float* __restrict__ sums)
{
    __shared__ __align__(16) char smem[81920];
    ushort* Xs   = (ushort*)smem;
    ushort* Wbuf = (ushort*)(smem + 49152);
    float*  dL   = (float*)(smem + 65536);                 // 8*64*3 f32
    int*    iL   = (int*)  (smem + 65536 + 6144);          // 8*64*3 i32
    float*  wgtL = (float*)(smem + 65536 + 12288);         // 64*3
    int*    idxL = (int*)  (smem + 65536 + 13056);         // 64*3

    const int t = threadIdx.x;
    const int lane = t & 63;
    const int w = __builtin_amdgcn_readfirstlane(t >> 6);  // 0..7
    const int b = blockIdx.y;
    const int n0 = blockIdx.x * 64;
    const int q = lane >> 4, r = lane & 15, r7 = r & 7;

    // W1 chunk0 prefetch overlaps the knn phase (into Wbuf buffer 0)
    #pragma unroll
    for (int jj = 0; jj < 2; ++jj)
        async_lds16((const char*)W1r + jj * 8192 + t * 16,
                    (char*)Wbuf + jj * 8192 + w * 1024);

    // ---- 3-NN: 8 waves x 256 candidates, lanes = queries ----
    {
        const int qi = n0 + lane;
        const float x1 = pos1[(b * 3 + 0) * N + qi];
        const float y1 = pos1[(b * 3 + 1) * N + qi];
        const float z1 = pos1[(b * 3 + 2) * N + qi];
        const float t1 = x1 * x1 + y1 * y1 + z1 * z1;
        const float4* __restrict__ pp = p2pack + b * S + w * 256;
        float d0 = 3.4e38f, d1 = 3.4e38f, d2 = 3.4e38f;
        int i0 = 0x7fffffff, i1 = 0x7fffffff, i2 = 0x7fffffff;
        #pragma unroll 8
        for (int i = 0; i < 256; ++i) {
            float4 p = pp[i];                       // uniform -> s_load
            float dot = fmaf(x1, p.x, fmaf(y1, p.y, z1 * p.z));
            float dd = fmaf(-2.f, dot, t1) + p.w;
            int s = w * 256 + i;
            bool c0 = dd < d0, c1 = dd < d1, c2 = dd < d2;
            i2 = c1 ? i1 : (c2 ? s : i2);
            i1 = c0 ? i0 : (c1 ? s : i1);
            i0 = c0 ? s : i0;
            float nd1 = __builtin_amdgcn_fmed3f(dd, d0, d1);
            float nd2 = __builtin_amdgcn_fmed3f(dd, d1, d2);
            d0 = fminf(d0, dd);
            d1 = nd1; d2 = nd2;
        }
        int base = (w * 64 + lane) * 3;
        dL[base + 0] = d0; dL[base + 1] = d1; dL[base + 2] = d2;
        iL[base + 0] = i0; iL[base + 1] = i1; iL[base + 2] = i2;
    }
    __syncthreads();
    if (t < 64) {
        float f0 = dL[t*3+0], fv1 = dL[t*3+1], fv2 = dL[t*3+2];
        int   j0 = iL[t*3+0], j1 = iL[t*3+1], j2 = iL[t*3+2];
        #pragma unroll
        for (int c = 1; c < 8; ++c) {
            int cb = (c * 64 + t) * 3;
            #pragma unroll
            for (int k = 0; k < 3; ++k) {
                float d = dL[cb + k]; int id = iL[cb + k];
                bool l0 = (d < f0)  || (d == f0  && id < j0);
                bool l1 = (d < fv1) || (d == fv1 && id < j1);
                bool l2 = (d < fv2) || (d == fv2 && id < j2);
                if (l0)      { fv2 = fv1; j2 = j1; fv1 = f0; j1 = j0; f0 = d; j0 = id; }
                else if (l1) { fv2 = fv1; j2 = j1; fv1 = d; j1 = id; }
                else if (l2) { fv2 = d; j2 = id; }
            }
        }
        float w0 = 1.f / fmaxf(f0, 1e-10f);
        float w1 = 1.f / fmaxf(fv1, 1e-10f);
        float w2 = 1.f / fmaxf(fv2, 1e-10f);
        float inv = 1.f / (w0 + w1 + w2);
        j0 = ((unsigned)j0 < S) ? j0 : 0;
        j1 = ((unsigned)j1 < S) ? j1 : 0;
        j2 = ((unsigned)j2 < S) ? j2 : 0;
        wgtL[t*3+0] = w0 * inv; wgtL[t*3+1] = w1 * inv; wgtL[t*3+2] = w2 * inv;
        idxL[t*3+0] = j0; idxL[t*3+1] = j1; idxL[t*3+2] = j2;
    }
    __syncthreads();

    // ---- X staging: fused interp (idx/wgt from LDS) + f1 tile ----
    {
        const int lp = t & 31, ro = t >> 5;               // ro 0..15
        #pragma unroll
        for (int it = 0; it < 4; ++it) {
            int rr = ro + 16 * it;
            int s0 = idxL[rr*3+0], s1 = idxL[rr*3+1], s2 = idxL[rr*3+2];
            float w0 = wgtL[rr*3+0], w1 = wgtL[rr*3+1], w2 = wgtL[rr*3+2];
            union { short8 s; ushort u[8]; } a, c, d, o;
            a.s = ld8(f2T + ((size_t)b * S + s0) * 256 + 8 * lp);
            c.s = ld8(f2T + ((size_t)b * S + s1) * 256 + 8 * lp);
            d.s = ld8(f2T + ((size_t)b * S + s2) * 256 + 8 * lp);
            #pragma unroll
            for (int j = 0; j < 8; ++j)
                o.u[j] = f2u(w0 * u2f(a.u[j]) + w1 * u2f(c.u[j]) + w2 * u2f(d.u[j]));
            *(short8*)(Xs + rr * 384 + ((lp ^ (rr & 7)) * 8)) = o.s;
        }
    }
    {
        const int lp = t & 15, ro = t >> 4;               // ro 0..31
        #pragma unroll
        for (int it = 0; it < 2; ++it) {
            int rr = ro + 32 * it;
            short8 v = ld8(f1T + ((size_t)b * N + n0 + rr) * 128 + 8 * lp);
            int c = 32 + lp;
            *(short8*)(Xs + rr * 384 + ((c ^ (rr & 7)) * 8)) = v;
        }
    }
    __syncthreads();

    // ---- GEMM1 (K=384, 12 chunks), 8 waves x 32 channels ----
    v4f acc[2][4];
    #pragma unroll
    for (int mt = 0; mt < 2; ++mt)
        #pragma unroll
        for (int nf = 0; nf < 4; ++nf) acc[mt][nf] = (v4f){0.f, 0.f, 0.f, 0.f};

    for (int kk = 0; kk < 12; ++kk) {
        if (kk < 11) {
            const char* g = (const char*)W1r + (kk + 1) * 16384;
            char* l = (char*)Wbuf + ((kk + 1) & 1) * 16384;
            #pragma unroll
            for (int jj = 0; jj < 2; ++jj)
                async_lds16(g + jj * 8192 + t * 16, l + jj * 8192 + w * 1024);
        }
        const ushort* Wb = Wbuf + (kk & 1) * 8192;
        short8 af[2], bf[4];
        #pragma unroll
        for (int mt = 0; mt < 2; ++mt)
            af[mt] = ld8(Wb + q * 2048 + (w * 32 + mt * 16 + r) * 8);
        #pragma unroll
        for (int nf = 0; nf < 4; ++nf)
            bf[nf] = ld8(Xs + (nf * 16 + r) * 384 + (((kk * 4 + q) ^ r7) * 8));
        #pragma unroll
        for (int mt = 0; mt < 2; ++mt)
            #pragma unroll
            for (int nf = 0; nf < 4; ++nf)
                acc[mt][nf] = __builtin_amdgcn_mfma_f32_16x16x32_bf16(
                    af[mt], bf[nf], acc[mt][nf], 0, 0, 0);
        __syncthreads();
    }

    // ---- epilogue: y -> HBM, stats -> atomics ----
    float* statS = (float*)Xs;
    float* statQ = statS + 256;
    #pragma unroll
    for (int mt = 0; mt < 2; ++mt) {
        int ob = w * 32 + mt * 16 + q * 4;
        float4 bi = *(const float4*)(bias1 + ob);
        float sj0 = 0, sj1 = 0, sj2 = 0, sj3 = 0;
        float qj0 = 0, qj1 = 0, qj2 = 0, qj3 = 0;
        #pragma unroll
        for (int nf = 0; nf < 4; ++nf) {
            int n = n0 + nf * 16 + r;
            float v0 = acc[mt][nf][0] + bi.x, v1 = acc[mt][nf][1] + bi.y;
            float v2 = acc[mt][nf][2] + bi.z, v3 = acc[mt][nf][3] + bi.w;
            ushort4 pk; pk.x = f2u(v0); pk.y = f2u(v1); pk.z = f2u(v2); pk.w = f2u(v3);
            *(ushort4*)(y + ((size_t)b * N + n) * 256 + ob) = pk;
            sj0 += v0; sj1 += v1; sj2 += v2; sj3 += v3;
            qj0 += v0 * v0; qj1 += v1 * v1; qj2 += v2 * v2; qj3 += v3 * v3;
        }
        #pragma unroll
        for (int m = 1; m <= 8; m <<= 1) {
            sj0 += __shfl_xor(sj0, m); sj1 += __shfl_xor(sj1, m);
            sj2 += __shfl_xor(sj2, m); sj3 += __shfl_xor(sj3, m);
            qj0 += __shfl_xor(qj0, m); qj1 += __shfl_xor(qj1, m);
            qj2 += __shfl_xor(qj2, m); qj3 += __shfl_xor(qj3, m);
        }
        if (r == 0) {
            statS[ob + 0] = sj0; statS[ob + 1] = sj1;
            statS[ob + 2] = sj2; statS[ob + 3] = sj3;
            statQ[ob + 0] = qj0; statQ[ob + 1] = qj1;
            statQ[ob + 2] = qj2; statQ[ob + 3] = qj3;
        }
    }
    __syncthreads();
    if (t < 256) {
        atomicAdd(&sums[t], statS[t]);
        atomicAdd(&sums[256 + t], statQ[t]);
    }
}

// ------------------------ GEMM2 (BN1+ReLU on load, in-place, fused stats) --
__global__ __launch_bounds__(512) void gemm2_kernel(
    const ushort* __restrict__ Wr, const float* __restrict__ bias,
    const float* __restrict__ sums1, const float* __restrict__ g1,
    const float* __restrict__ be1,
    ushort* __restrict__ y, float* __restrict__ sums)
{
    __shared__ __align__(16) ushort Xs[64 * 256];      // 32 KB
    __shared__ __align__(16) ushort Wbuf[2 * 8192];    // 32 KB
    __shared__ float ssA[256], ssB[256];
    const int t = threadIdx.x;
    const int b = blockIdx.y;
    const int n0 = blockIdx.x * 64;
    const int w = t >> 6, lane = t & 63;
    const int q = lane >> 4, r = lane & 15, r7 = r & 7;

    {
        const char* g0 = (const char*)Wr;
        #pragma unroll
        for (int jj = 0; jj < 2; ++jj)
            async_lds16(g0 + jj * 8192 + t * 16,
                        (char*)Wbuf + jj * 8192 + w * 1024);
    }

    if (t < 256) {
        float sv = sums1[t], qv = sums1[256 + t];
        float mean = sv * (1.f / 32768.f);
        float var = qv * (1.f / 32768.f) - mean * mean;
        float rstd = rsqrtf(var + 1e-5f);
        float sc = g1[t] * rstd;
        ssA[t] = sc;
        ssB[t] = be1[t] - mean * sc;
    }
    __syncthreads();

    {
        const int lp = t & 31, ro = t >> 5;               // ro 0..15
        #pragma unroll
        for (int it = 0; it < 4; ++it) {
            int rr = ro + 16 * it;
            union { short8 s; ushort u[8]; } v, o;
            v.s = ld8(y + ((size_t)b * N + n0 + rr) * 256 + 8 * lp);
            #pragma unroll
            for (int j = 0; j < 8; ++j)
                o.u[j] = f2u(fmaxf(u2f(v.u[j]) * ssA[8 * lp + j] + ssB[8 * lp + j], 0.f));
            *(short8*)(Xs + rr * 256 + ((lp ^ (rr & 7)) * 8)) = o.s;
        }
    }
    __syncthreads();

    v4f acc[2][4];
    #pragma unroll
    for (int mt = 0; mt < 2; ++mt)
        #pragma unroll
        for (int nf = 0; nf < 4; ++nf) acc[mt][nf] = (v4f){0.f, 0.f, 0.f, 0.f};

    for (int kk = 0; kk < 8; ++kk) {
        if (kk < 7) {
            const char* g = (const char*)Wr + (kk + 1) * 16384;
            char* l = (char*)Wbuf + ((kk + 1) & 1) * 16384;
            #pragma unroll
            for (int jj = 0; jj < 2; ++jj)
                async_lds16(g + jj * 8192 + t * 16, l + jj * 8192 + w * 1024);
        }
        const ushort* Wb = Wbuf + (kk & 1) * 8192;
        short8 af[2], bf[4];
        #pragma unroll
        for (int mt = 0; mt < 2; ++mt)
            af[mt] = ld8(Wb + q * 2048 + (w * 32 + mt * 16 + r) * 8);
        #pragma unroll
        for (int nf = 0; nf < 4; ++nf)
            bf[nf] = ld8(Xs + (nf * 16 + r) * 256 + (((kk * 4 + q) ^ r7) * 8));
        #pragma unroll
        for (int mt = 0; mt < 2; ++mt)
            #pragma unroll
            for (int nf = 0; nf < 4; ++nf)
                acc[mt][nf] = __builtin_amdgcn_mfma_f32_16x16x32_bf16(
                    af[mt], bf[nf], acc[mt][nf], 0, 0, 0);
        __syncthreads();
    }

    float* statS = (float*)Xs;
    float* statQ = statS + 256;
    #pragma unroll
    for (int mt = 0; mt < 2; ++mt) {
        int ob = w * 32 + mt * 16 + q * 4;
        float4 bi = *(const float4*)(bias + ob);
        float sj0 = 0, sj1 = 0, sj2 = 0, sj3 = 0;
        float qj0 = 0, qj1 = 0, qj2 = 0, qj3 = 0;
        #pragma unroll
        for (int nf = 0; nf < 4; ++nf) {
            int n = n0 + nf * 16 + r;
            float v0 = acc[mt][nf][0] + bi.x, v1 = acc[mt][nf][1] + bi.y;
            float v2 = acc[mt][nf][2] + bi.z, v3 = acc[mt][nf][3] + bi.w;
            ushort4 pk; pk.x = f2u(v0); pk.y = f2u(v1); pk.z = f2u(v2); pk.w = f2u(v3);
            *(ushort4*)(y + ((size_t)b * N + n) * 256 + ob) = pk;
            sj0 += v0; sj1 += v1; sj2 += v2; sj3 += v3;
            qj0 += v0 * v0; qj1 += v1 * v1; qj2 += v2 * v2; qj3 += v3 * v3;
        }
        #pragma unroll
        for (int m = 1; m <= 8; m <<= 1) {
            sj0 += __shfl_xor(sj0, m); sj1 += __shfl_xor(sj1, m);
            sj2 += __shfl_xor(sj2, m); sj3 += __shfl_xor(sj3, m);
            qj0 += __shfl_xor(qj0, m); qj1 += __shfl_xor(qj1, m);
            qj2 += __shfl_xor(qj2, m); qj3 += __shfl_xor(qj3, m);
        }
        if (r == 0) {
            statS[ob + 0] = sj0; statS[ob + 1] = sj1;
            statS[ob + 2] = sj2; statS[ob + 3] = sj3;
            statQ[ob + 0] = qj0; statQ[ob + 1] = qj1;
            statQ[ob + 2] = qj2; statQ[ob + 3] = qj3;
        }
    }
    __syncthreads();
    if (t < 256) {
        atomicAdd(&sums[t], statS[t]);
        atomicAdd(&sums[256 + t], statQ[t]);
    }
}

// ------------- final: BN2+ReLU + transpose to [B,256,N] fp32 (64x64) ------
__global__ __launch_bounds__(256) void final_kernel(
    const ushort* __restrict__ Y, const float* __restrict__ sums2,
    const float* __restrict__ g2, const float* __restrict__ be2,
    float* __restrict__ out)
{
    __shared__ float tl[64][65];
    __shared__ float ssA[64], ssB[64];
    const int t = threadIdx.x;
    const int b = blockIdx.z;
    const int n0 = blockIdx.x * 64, c0 = blockIdx.y * 64;

    if (t < 64) {
        int c = c0 + t;
        float sv = sums2[c], qv = sums2[256 + c];
        float mean = sv * (1.f / 32768.f);
        float var = qv * (1.f / 32768.f) - mean * mean;
        float rstd = rsqrtf(var + 1e-5f);
        float sc = g2[c] * rstd;
        ssA[t] = sc;
        ssB[t] = be2[c] - mean * sc;
    }
    __syncthreads();

    const int nl = t >> 3, cho = 8 * (t & 7);
    #pragma unroll
    for (int it = 0; it < 2; ++it) {
        int n = nl + 32 * it;
        union { short8 s; ushort u[8]; } v;
        v.s = ld8(Y + ((size_t)b * N + n0 + n) * 256 + c0 + cho);
        #pragma unroll
        for (int j = 0; j < 8; ++j)
            tl[n][cho + j] = fmaxf(u2f(v.u[j]) * ssA[cho + j] + ssB[cho + j], 0.f);
    }
    __syncthreads();

    const int cl = t >> 4, n4 = (t & 15) * 4;
    #pragma unroll
    for (int it = 0; it < 4; ++it) {
        int c = cl + 16 * it;
        float4 v;
        v.x = tl[n4 + 0][c]; v.y = tl[n4 + 1][c];
        v.z = tl[n4 + 2][c]; v.w = tl[n4 + 3][c];
        *(float4*)(out + ((size_t)b * 256 + c0 + c) * N + n0 + n4) = v;
    }
}

// ------------------------------------------------------------ launch -----
extern "C" void kernel_launch(void* const* d_in, const int* in_sizes, int n_in,
                              void* d_out, int out_size, void* d_ws, size_t ws_size,
                              hipStream_t stream)
{
    (void)in_sizes; (void)n_in; (void)out_size;
    if (ws_size < (30u << 20)) return;

    const float* pos1 = (const float*)d_in[0];
    const float* pos2 = (const float*)d_in[1];
    const float* f1   = (const float*)d_in[2];
    const float* f2   = (const float*)d_in[3];
    const float* W1   = (const float*)d_in[4];
    const float* b1   = (const float*)d_in[5];
    const float* g1   = (const float*)d_in[6];
    const float* be1  = (const float*)d_in[7];
    const float* W2   = (const float*)d_in[8];
    const float* b2   = (const float*)d_in[9];
    const float* g2   = (const float*)d_in[10];
    const float* be2  = (const float*)d_in[11];

    char* ws = (char*)d_ws;
    float*  sums1  = (float*)ws;                               // 512 f32
    float*  sums2  = sums1 + 512;                              // 512 f32
    ushort* W1r    = (ushort*)(ws + 4096);                     // 192 KB
    ushort* W2r    = (ushort*)(ws + 4096 + 196608);            // 128 KB
    float4* p2pack = (float4*)(ws + 4096 + 196608 + 131072);   // 128 KB
    ushort* f2T    = (ushort*)(ws + (1u << 19));               // 4 MB
    ushort* f1T    = (ushort*)(ws + (1u << 19) + (4u << 20));  // 8 MB
    ushort* y      = (ushort*)(ws + (1u << 19) + (12u << 20)); // 16 MB

    prep_all<<<1652, 256, 0, stream>>>(W1, W2, pos2, f2, f1,
                                       W1r, W2r, p2pack, sums1, f2T, f1T);

    knn_gemm1<<<dim3(N / 64, B), 512, 0, stream>>>(
        pos1, p2pack, W1r, b1, f2T, f1T, y, sums1);

    gemm2_kernel<<<dim3(N / 64, B), 512, 0, stream>>>(
        W2r, b2, sums1, g1, be1, y, sums2);

    final_kernel<<<dim3(N / 64, 256 / 64, B), 256, 0, stream>>>(
        y, sums2, g2, be2, (float*)d_out);
}